// Round 5
// baseline (442.056 us; speedup 1.0000x reference)
//
#include <hip/hip_runtime.h>
#include <cstddef>

// ---------------------------------------------------------------------------
// CLSTMCell fused as one bf16 GEMM + epilogue.
//   X (4096 x 4096)  = [xr | xi | hr | hi] rows  (bf16, packed in ws)
//   W (8192 x 4096)  rows n = o*8 + g*2 + p, k-quarters [UwR,-UwI,WwR,-WwI] (p=0)
//                                            [UwI, UwR, WwI, WwR]           (p=1)
//   z = X @ W^T + bias ; epilogue: gates -> c_t, h_t  (fp32 out)
//
// R8: (a) GEMM boundary fixed to true counted-vmcnt: ALL 8 stage issues at
//   tile top (full-tile lead ~2500cyc >> 900cyc HBM latency) so the boundary
//   wait vmcnt(8) completes instantly; R7 spread issues across phases and the
//   last ones (phase 3, ~600cyc early) forced a real stall at the vmcnt(0)
//   drain every tile. Two-barrier boundary closes the buffer-overwrite race:
//   barrier1 (all waves done reading buf^1 = tile kt-1) -> issue 8 into buf^1
//   -> vmcnt(8) (completes tile kt's 8, issued one full tile ago) -> barrier2
//   (kt's data visible to all).
//   (b) pack_all given 2x MLP: 64B/thread (X: 4 loads in flight, was 2 +
//   full-drain; W: 8, was 4), half the waves. pack was ~160us vs ~40us
//   streaming roofline -> latency-bound theory.
//
// Fixed lessons (do not regress):
//   * rule #20: EVERY acc/af index must be compile-time (full unroll) or the
//     array demotes to scratch (R5: 134MB/dispatch scratch round trip).
//   * launch_bounds 2nd arg for 512-thr blocks is a no-op; keep plain (512).
//   * R7: register-pipelined phases (reads for p+1 issued before p's MFMAs,
//     ping-pong af, static idx) beat barrier-locked phases: 41% -> 48%.
// ---------------------------------------------------------------------------

typedef short bf16x8 __attribute__((ext_vector_type(8)));   // 8 bf16 (4 VGPRs)
typedef float f32x4  __attribute__((ext_vector_type(4)));
typedef unsigned int u32x4 __attribute__((ext_vector_type(4)));

static constexpr int KDIM = 4096;
static constexpr size_t HOFF = (size_t)4096 * 2048;   // out offset of c_t

__device__ __forceinline__ unsigned short f2bf(float f) {
    unsigned u = __float_as_uint(f);
    u += 0x7FFF + ((u >> 16) & 1);      // RNE
    return (unsigned short)(u >> 16);
}

__device__ __forceinline__ u32x4 pack8(float4 a, float4 b) {
    u32x4 v;
    v.x = (unsigned)f2bf(a.x) | ((unsigned)f2bf(a.y) << 16);
    v.y = (unsigned)f2bf(a.z) | ((unsigned)f2bf(a.w) << 16);
    v.z = (unsigned)f2bf(b.x) | ((unsigned)f2bf(b.y) << 16);
    v.w = (unsigned)f2bf(b.z) | ((unsigned)f2bf(b.w) << 16);
    return v;
}

__device__ __forceinline__ float4 neg4(float4 v) {
    return make_float4(-v.x, -v.y, -v.z, -v.w);
}

__device__ __forceinline__ void async16(const void* g, void* l) {
    __builtin_amdgcn_global_load_lds(
        (const __attribute__((address_space(1))) unsigned int*)g,
        (__attribute__((address_space(3))) unsigned int*)l,
        16, 0, 0);
}

__device__ __forceinline__ float sigm(float x) { return 1.0f / (1.0f + __expf(-x)); }
__device__ __forceinline__ float tanh_(float x) {
    float e = __expf(2.0f * x);          // |x| <~ 10 here, no overflow
    return (e - 1.0f) / (e + 1.0f);
}

// ------------------ merged pack: X rows + W (signs folded) + bias -----------
// 64B loaded per thread (4/8 loads in flight) for memory-level parallelism.
__global__ __launch_bounds__(256) void pack_all(
    const float* __restrict__ input, const float* __restrict__ hx,
    const float* __restrict__ Uw_r, const float* __restrict__ Uw_i,
    const float* __restrict__ Ww_r, const float* __restrict__ Ww_i,
    const float* __restrict__ Ub_r, const float* __restrict__ Ub_i,
    const float* __restrict__ Wb_r, const float* __restrict__ Wb_i,
    unsigned short* __restrict__ Xb, unsigned short* __restrict__ Wb16,
    float* __restrict__ biasp) {
    int bid = blockIdx.x;
    if (bid < 4096) {
        // ---- pack X = [input | h_x] rows: 16 floats -> 16 bf16 per thread ----
        int idx = bid * 256 + threadIdx.x;          // 1,048,576 chunks of 16
        int r    = idx >> 8;                        // row 0..4095
        int gcol = (idx & 255) * 16;                // 0..4080 (never crosses 2048)
        const float* src = (gcol < 2048) ? (input + (size_t)r * 2048 + gcol)
                                         : (hx    + (size_t)r * 2048 + (gcol - 2048));
        float4 f0 = *(const float4*)src;
        float4 f1 = *(const float4*)(src + 4);
        float4 f2 = *(const float4*)(src + 8);
        float4 f3 = *(const float4*)(src + 12);
        *(u32x4*)(Xb + (size_t)idx * 16)     = pack8(f0, f1);
        *(u32x4*)(Xb + (size_t)idx * 16 + 8) = pack8(f2, f3);
    } else {
        // ---- pack W row-pairs + bias: 16 k-elems of both rows per thread ----
        int idx = (bid - 4096) * 256 + threadIdx.x; // 1,048,576
        int np = idx >> 8;                          // o*4 + g, 0..4095
        int k  = (idx & 255) * 16;                  // 0..4080 (same q for all 16)
        int o = np >> 2, g = np & 3;
        int q = k >> 10, d = k & 1023;              // k-quarter, offset within
        size_t sidx = (size_t)g * (1024 * 1024) + (size_t)o * 1024 + d;
        const float* srcR = (q < 2 ? Uw_r : Ww_r) + sidx;
        const float* srcI = (q < 2 ? Uw_i : Ww_i) + sidx;
        float4 r0 = *(const float4*)srcR;        float4 r1 = *(const float4*)(srcR + 4);
        float4 r2 = *(const float4*)(srcR + 8);  float4 r3 = *(const float4*)(srcR + 12);
        float4 i0 = *(const float4*)srcI;        float4 i1 = *(const float4*)(srcI + 4);
        float4 i2 = *(const float4*)(srcI + 8);  float4 i3 = *(const float4*)(srcI + 12);
        int n0 = o * 8 + g * 2;
        u32x4 p00, p01, p10, p11;                // rows n0 / n0+1, halves 0/1
        if (q & 1) {
            p00 = pack8(neg4(i0), neg4(i1)); p01 = pack8(neg4(i2), neg4(i3));
            p10 = pack8(r0, r1);             p11 = pack8(r2, r3);
        } else {
            p00 = pack8(r0, r1);             p01 = pack8(r2, r3);
            p10 = pack8(i0, i1);             p11 = pack8(i2, i3);
        }
        *(u32x4*)(Wb16 + (size_t)n0 * KDIM + k)           = p00;
        *(u32x4*)(Wb16 + (size_t)n0 * KDIM + k + 8)       = p01;
        *(u32x4*)(Wb16 + (size_t)(n0 + 1) * KDIM + k)     = p10;
        *(u32x4*)(Wb16 + (size_t)(n0 + 1) * KDIM + k + 8) = p11;
        if (k == 0) {
            size_t bi = (size_t)g * 1024 + o;
            biasp[n0]     = Ub_r[bi] + Wb_r[bi];
            biasp[n0 + 1] = Ub_i[bi] + Wb_i[bi];
        }
    }
}

// ------------------------- GEMM + fused epilogue ----------------------------
// block: 512 threads (8 waves, 2Mx4N), C-tile 256x256, BK=64, 16x16x32 MFMA.
// LDS: 2 buffers x (A 32KB + B 32KB) = 128 KiB (dynamic; attribute set on host).
// Per-wave output 128x64 -> acc[8][4] f32x4 (128 regs, AGPR-eligible).
__global__ __launch_bounds__(512) void clstm_gemm(
    const unsigned short* __restrict__ Xb,    // 4096 x 4096 bf16
    const unsigned short* __restrict__ Wb,    // 8192 x 4096 bf16
    const float* __restrict__ biasp,          // 8192
    const float* __restrict__ c_x,            // 4096 x 2048 fp32
    float* __restrict__ out) {
    extern __shared__ char smem[];            // 131072 bytes

    const int tid  = threadIdx.x;
    const int lane = tid & 63;
    const int wave = tid >> 6;                // 0..7
    const int wm = wave >> 2, wn = wave & 3;  // 2 x 4 wave grid
    const int quad = lane >> 4, col16 = lane & 15;

    // XCD-contiguous block swizzle: nwg=512 (8|512 -> bijective), then 4x8
    // supertiles so 32 consecutive swz share 4 A-panels + 8 B-panels.
    const int bid = blockIdx.x;
    const int swz = (bid & 7) * 64 + (bid >> 3);
    const int st = swz >> 5, wi = swz & 31;
    const int mtile = (st & 3) * 4 + (wi & 3);      // 0..15
    const int ntile = (st >> 2) * 8 + (wi >> 2);    // 0..31

    // staging: per K-tile 8 global_load_lds x 16B per thread (4 A + 4 B).
    // chunk id for load i = i*512 + tid -> LDS row id>>3, slot id&7 (linear
    // dest); global source pre-swizzled: chunk fetched = slot ^ (row&7).
    const int srow  = tid >> 3;               // 0..63
    const int sslot = tid & 7;
    const unsigned short* pa[4];
    const unsigned short* pb[4];
#pragma unroll
    for (int i = 0; i < 4; ++i) {
        const int rowA = i * 64 + srow;       // 0..255
        const int c = sslot ^ (rowA & 7);
        pa[i] = Xb + (size_t)(mtile * 256 + rowA) * KDIM + c * 8;
        pb[i] = Wb + (size_t)(ntile * 256 + rowA) * KDIM + c * 8;
    }

    f32x4 acc[8][4] = {};

    // prologue: stage tile 0 into buf0
#pragma unroll
    for (int i = 0; i < 4; ++i) {
        async16(pa[i], smem + i * 8192 + wave * 1024);
        async16(pb[i], smem + 32768 + i * 8192 + wave * 1024);
        pa[i] += 64; pb[i] += 64;
    }

    const int rA0 = wm * 128 + col16;         // + p*32 + f*16
    const int rB0 = wn * 64 + col16;          // + n*16

#pragma unroll 2
    for (int kt = 0; kt < 64; ++kt) {
        char* sA  = smem + (kt & 1) * 65536;
        char* sB  = sA + 32768;
        char* sAn = smem + (((kt & 1) ^ 1)) * 65536;
        char* sBn = sAn + 32768;

        // Boundary B_kt (two barriers, counted vmcnt):
        //   barrier1: all waves finished reading buf^1 (tile kt-1's data).
        __builtin_amdgcn_s_barrier();
        if (kt < 63) {
            // issue ALL 8 stages for kt+1 into buf^1 now (full-tile lead);
#pragma unroll
            for (int i = 0; i < 4; ++i) {
                async16(pa[i], sAn + i * 8192 + wave * 1024);
                async16(pb[i], sBn + i * 8192 + wave * 1024);
                pa[i] += 64; pb[i] += 64;
            }
            // completes the 8 OLDEST = tile kt's own loads, issued one full
            // tile (~2500cyc >> 900cyc HBM) ago -> returns ~immediately.
            asm volatile("s_waitcnt vmcnt(8)" ::: "memory");
        } else {
            asm volatile("s_waitcnt vmcnt(0)" ::: "memory");
        }
        //   barrier2: every wave's vmcnt wait passed -> kt's data visible.
        __builtin_amdgcn_s_barrier();

        // B fragments for the whole K-tile + A fragments for phase 0.
        bf16x8 bfr[4][2];
#pragma unroll
        for (int n = 0; n < 4; ++n)
#pragma unroll
            for (int ks = 0; ks < 2; ++ks) {
                const int r = rB0 + n * 16;
                const int ch = (ks * 4 + quad) ^ (r & 7);
                bfr[n][ks] = *(const bf16x8*)(sB + r * 128 + ch * 16);
            }
        bf16x8 af[2][2][2];                   // [pingpong][f][ks], static idx
#pragma unroll
        for (int f = 0; f < 2; ++f)
#pragma unroll
            for (int ks = 0; ks < 2; ++ks) {
                const int r = rA0 + f * 16;
                const int ch = (ks * 4 + quad) ^ (r & 7);
                af[0][f][ks] = *(const bf16x8*)(sA + r * 128 + ch * 16);
            }

        // 4 phases, software-pipelined by one: phase p issues A-reads for
        // p+1 (into af[nxt]) then runs MFMAs on af[cur] (read last phase,
        // already retired -> compiler emits lgkmcnt(4), no drain). The
        // ds_reads execute on the LDS pipe WHILE MFMAs run. No barriers.
#pragma unroll
        for (int p = 0; p < 4; ++p) {
            const int cur = p & 1, nxt = cur ^ 1;
            if (p < 3) {
#pragma unroll
                for (int f = 0; f < 2; ++f)
#pragma unroll
                    for (int ks = 0; ks < 2; ++ks) {
                        const int r = rA0 + (p + 1) * 32 + f * 16;
                        const int ch = (ks * 4 + quad) ^ (r & 7);
                        af[nxt][f][ks] = *(const bf16x8*)(sA + r * 128 + ch * 16);
                    }
            }
            __builtin_amdgcn_s_setprio(1);
#pragma unroll
            for (int f = 0; f < 2; ++f)
#pragma unroll
                for (int n = 0; n < 4; ++n) {
                    acc[p * 2 + f][n] = __builtin_amdgcn_mfma_f32_16x16x32_bf16(
                        af[cur][f][0], bfr[n][0], acc[p * 2 + f][n], 0, 0, 0);
                    acc[p * 2 + f][n] = __builtin_amdgcn_mfma_f32_16x16x32_bf16(
                        af[cur][f][1], bfr[n][1], acc[p * 2 + f][n], 0, 0, 0);
                }
            __builtin_amdgcn_s_setprio(0);
        }
    }

    // ---- epilogue: per-wave LDS round trip, C-layout -> (row, o) layout ----
    // Wave tile = 128 rows x 64 cols. 8 passes of (32 rows x 32 cols):
    // pass = seg (0..3, row segment) x h (0..1, col half). zs is WAVE-PRIVATE
    // (disjoint 8KB regions): one barrier total, then intra-wave ordering only.
    // FULLY UNROLLED (rule #20): every acc index must be compile-time or the
    // whole acc array is demoted to scratch (134MB/dispatch round trip).
    __syncthreads();                          // all K-loop LDS traffic done
    float* zs = (float*)(smem + wave * 8192); // 32 rows x 40 f32 = 5120B used
    const float* bp = biasp + ntile * 256 + wn * 64;
    const int o_idx = lane & 3;
    const int rgrp  = lane >> 2;              // 0..15

#pragma unroll
    for (int pass = 0; pass < 8; ++pass) {
        const int seg = pass >> 1;            // row segment: acc mf = seg*2 + {0,1}
        const int h   = pass & 1;             // col half:   acc nf = h*2 + {0,1}
#pragma unroll
        for (int mf2 = 0; mf2 < 2; ++mf2)
#pragma unroll
            for (int tl = 0; tl < 2; ++tl) {
                int nf = h * 2 + tl;
                int colz = tl * 16 + col16;
#pragma unroll
                for (int r = 0; r < 4; ++r)
                    zs[(mf2 * 16 + quad * 4 + r) * 40 + colz] = acc[seg * 2 + mf2][nf][r];
            }
        // intra-wave RAW through LDS: compiler inserts lgkmcnt wait

        float4 bb0 = *(const float4*)(bp + h * 32 + o_idx * 8);
        float4 bb1 = *(const float4*)(bp + h * 32 + o_idx * 8 + 4);
        int o_glob = ntile * 32 + wn * 8 + h * 4 + o_idx;

#pragma unroll
        for (int t = 0; t < 2; ++t) {
            int rowz = rgrp + t * 16;         // 0..31 within segment
            const float* zp = zs + rowz * 40 + o_idx * 8;
            float4 z0 = *(const float4*)zp;
            float4 z1 = *(const float4*)(zp + 4);
            int b = mtile * 256 + wm * 128 + seg * 32 + rowz;

            float fr = sigm(z0.x + bb0.x), fi = sigm(z0.y + bb0.y);
            float ir = sigm(z0.z + bb0.z), ii = sigm(z0.w + bb0.w);
            float ar = tanh_(z1.x + bb1.x), ai = tanh_(z1.y + bb1.y);
            float og_r = sigm(z1.z + bb1.z), og_i = sigm(z1.w + bb1.w);

            float cr = c_x[(size_t)b * 2048 + o_glob];
            float ci = c_x[(size_t)b * 2048 + 1024 + o_glob];

            float ct_r = (cr * fr - ci * fi) + (ar * ir - ai * ii);
            float ct_i = (cr * fi + ci * fr) + (ar * ii + ai * ir);
            float tr = tanh_(ct_r), ti = tanh_(ct_i);
            float ht_r = og_r * tr - og_i * ti;
            float ht_i = og_r * ti + og_i * tr;

            out[(size_t)b * 2048 + o_glob]               = ht_r;
            out[(size_t)b * 2048 + 1024 + o_glob]        = ht_i;
            out[HOFF + (size_t)b * 2048 + o_glob]        = ct_r;
            out[HOFF + (size_t)b * 2048 + 1024 + o_glob] = ct_i;
        }
        if (pass < 7)                          // drain zs reads before next pass
            asm volatile("s_waitcnt lgkmcnt(0)" ::: "memory");  // overwrites zs
    }
}

// ---------------------------------------------------------------------------
extern "C" void kernel_launch(void* const* d_in, const int* in_sizes, int n_in,
                              void* d_out, int out_size, void* d_ws, size_t ws_size,
                              hipStream_t stream) {
    const float* input = (const float*)d_in[0];
    const float* h_x   = (const float*)d_in[1];
    const float* c_x   = (const float*)d_in[2];
    const float* Uw_r  = (const float*)d_in[3];
    const float* Uw_i  = (const float*)d_in[4];
    const float* Ub_r  = (const float*)d_in[5];
    const float* Ub_i  = (const float*)d_in[6];
    const float* Ww_r  = (const float*)d_in[7];
    const float* Ww_i  = (const float*)d_in[8];
    const float* Wb_r  = (const float*)d_in[9];
    const float* Wb_i  = (const float*)d_in[10];
    float* out = (float*)d_out;

    // ws layout: X bf16 (32MB) | Wbig bf16 (64MB) | bias fp32 (32KB)  ~= 96MB
    unsigned short* Xb   = (unsigned short*)d_ws;
    unsigned short* Wb16 = Xb + (size_t)4096 * 4096;
    float* biasp = (float*)(Wb16 + (size_t)8192 * 4096);

    static bool s_attr = false;               // host-side, not a stream op:
    if (!s_attr) {                            // graph-capture safe
        hipFuncSetAttribute((const void*)clstm_gemm,
                            hipFuncAttributeMaxDynamicSharedMemorySize, 131072);
        s_attr = true;
    }

    pack_all<<<8192, 256, 0, stream>>>(input, h_x, Uw_r, Uw_i, Ww_r, Ww_i,
                                       Ub_r, Ub_i, Wb_r, Wb_i, Xb, Wb16, biasp);
    clstm_gemm<<<512, 512, 131072, stream>>>(Xb, Wb16, biasp, c_x, out);
}

// Round 6
// 435.912 us; speedup vs baseline: 1.0141x; 1.0141x over previous
//
#include <hip/hip_runtime.h>
#include <cstddef>

// ---------------------------------------------------------------------------
// CLSTMCell fused as one bf16 GEMM + epilogue.
//   X (4096 x 4096)  = [xr | xi | hr | hi] rows  (bf16, packed in ws)
//   W (8192 x 4096)  rows n = o*8 + g*2 + p, k-quarters [UwR,-UwI,WwR,-WwI] (p=0)
//                                            [UwI, UwR, WwI, WwR]           (p=1)
//   z = X @ W^T + bias ; epilogue: gates -> c_t, h_t  (fp32 out)
//
// R9: back to R7's empirically-best boundary (single barrier + vmcnt(0),
//   stage issues spread across phases) with two targeted fixes:
//   (1) phase-0 dependency split: hoist only bfr[0..1]+af0 (8 reads); read
//       bfr[2..3] inside phase 0; phase-0 MFMAs ordered n={0,1} then {2,3}.
//       Cuts the post-barrier serial lgkm chain from 12 reads (~1150cyc/CU)
//       to 8 (~600), retiring bfr[2..3] under the first 8 MFMAs.
//   (2) stage issues at phases 0/1/2 (4/2/2), none in phase 3: last issue
//       ~1200cyc before the boundary vmcnt(0) > ~900cyc HBM latency, so the
//       drain is ~free. (R8 fixed this with all-8-at-top + TWO barriers and
//       REGRESSED 256->281us: the extra barrier + clumped VMEM issue burst
//       cost more than the stall it removed. Do not re-clump.)
//
// Fixed lessons (do not regress):
//   * rule #20: EVERY acc/af index must be compile-time (full unroll) or the
//     array demotes to scratch (R5: 134MB/dispatch scratch round trip).
//   * launch_bounds 2nd arg for 512-thr blocks is a no-op; keep plain (512).
//   * R7: register-pipelined phases (reads for p+1 issued before p's MFMAs,
//     ping-pong af, static idx) beat barrier-locked phases: 41% -> 48%.
//   * VGPR wall: acc=128 pins us at the 256-unified-regs/wave tier (2 waves/
//     SIMD needed: 8 waves/block, 1 block/CU). arch VGPR must stay <=128;
//     no extra whole-tile register prefetch (e.g. next-tile bfr) fits.
// ---------------------------------------------------------------------------

typedef short bf16x8 __attribute__((ext_vector_type(8)));   // 8 bf16 (4 VGPRs)
typedef float f32x4  __attribute__((ext_vector_type(4)));
typedef unsigned int u32x4 __attribute__((ext_vector_type(4)));

static constexpr int KDIM = 4096;
static constexpr size_t HOFF = (size_t)4096 * 2048;   // out offset of c_t

__device__ __forceinline__ unsigned short f2bf(float f) {
    unsigned u = __float_as_uint(f);
    u += 0x7FFF + ((u >> 16) & 1);      // RNE
    return (unsigned short)(u >> 16);
}

__device__ __forceinline__ u32x4 pack8(float4 a, float4 b) {
    u32x4 v;
    v.x = (unsigned)f2bf(a.x) | ((unsigned)f2bf(a.y) << 16);
    v.y = (unsigned)f2bf(a.z) | ((unsigned)f2bf(a.w) << 16);
    v.z = (unsigned)f2bf(b.x) | ((unsigned)f2bf(b.y) << 16);
    v.w = (unsigned)f2bf(b.z) | ((unsigned)f2bf(b.w) << 16);
    return v;
}

__device__ __forceinline__ float4 neg4(float4 v) {
    return make_float4(-v.x, -v.y, -v.z, -v.w);
}

__device__ __forceinline__ void async16(const void* g, void* l) {
    __builtin_amdgcn_global_load_lds(
        (const __attribute__((address_space(1))) unsigned int*)g,
        (__attribute__((address_space(3))) unsigned int*)l,
        16, 0, 0);
}

__device__ __forceinline__ float sigm(float x) { return 1.0f / (1.0f + __expf(-x)); }
__device__ __forceinline__ float tanh_(float x) {
    float e = __expf(2.0f * x);          // |x| <~ 10 here, no overflow
    return (e - 1.0f) / (e + 1.0f);
}

// ------------------ merged pack: X rows + W (signs folded) + bias -----------
// 64B loaded per thread (4/8 loads in flight) for memory-level parallelism.
__global__ __launch_bounds__(256) void pack_all(
    const float* __restrict__ input, const float* __restrict__ hx,
    const float* __restrict__ Uw_r, const float* __restrict__ Uw_i,
    const float* __restrict__ Ww_r, const float* __restrict__ Ww_i,
    const float* __restrict__ Ub_r, const float* __restrict__ Ub_i,
    const float* __restrict__ Wb_r, const float* __restrict__ Wb_i,
    unsigned short* __restrict__ Xb, unsigned short* __restrict__ Wb16,
    float* __restrict__ biasp) {
    int bid = blockIdx.x;
    if (bid < 4096) {
        // ---- pack X = [input | h_x] rows: 16 floats -> 16 bf16 per thread ----
        int idx = bid * 256 + threadIdx.x;          // 1,048,576 chunks of 16
        int r    = idx >> 8;                        // row 0..4095
        int gcol = (idx & 255) * 16;                // 0..4080 (never crosses 2048)
        const float* src = (gcol < 2048) ? (input + (size_t)r * 2048 + gcol)
                                         : (hx    + (size_t)r * 2048 + (gcol - 2048));
        float4 f0 = *(const float4*)src;
        float4 f1 = *(const float4*)(src + 4);
        float4 f2 = *(const float4*)(src + 8);
        float4 f3 = *(const float4*)(src + 12);
        *(u32x4*)(Xb + (size_t)idx * 16)     = pack8(f0, f1);
        *(u32x4*)(Xb + (size_t)idx * 16 + 8) = pack8(f2, f3);
    } else {
        // ---- pack W row-pairs + bias: 16 k-elems of both rows per thread ----
        int idx = (bid - 4096) * 256 + threadIdx.x; // 1,048,576
        int np = idx >> 8;                          // o*4 + g, 0..4095
        int k  = (idx & 255) * 16;                  // 0..4080 (same q for all 16)
        int o = np >> 2, g = np & 3;
        int q = k >> 10, d = k & 1023;              // k-quarter, offset within
        size_t sidx = (size_t)g * (1024 * 1024) + (size_t)o * 1024 + d;
        const float* srcR = (q < 2 ? Uw_r : Ww_r) + sidx;
        const float* srcI = (q < 2 ? Uw_i : Ww_i) + sidx;
        float4 r0 = *(const float4*)srcR;        float4 r1 = *(const float4*)(srcR + 4);
        float4 r2 = *(const float4*)(srcR + 8);  float4 r3 = *(const float4*)(srcR + 12);
        float4 i0 = *(const float4*)srcI;        float4 i1 = *(const float4*)(srcI + 4);
        float4 i2 = *(const float4*)(srcI + 8);  float4 i3 = *(const float4*)(srcI + 12);
        int n0 = o * 8 + g * 2;
        u32x4 p00, p01, p10, p11;                // rows n0 / n0+1, halves 0/1
        if (q & 1) {
            p00 = pack8(neg4(i0), neg4(i1)); p01 = pack8(neg4(i2), neg4(i3));
            p10 = pack8(r0, r1);             p11 = pack8(r2, r3);
        } else {
            p00 = pack8(r0, r1);             p01 = pack8(r2, r3);
            p10 = pack8(i0, i1);             p11 = pack8(i2, i3);
        }
        *(u32x4*)(Wb16 + (size_t)n0 * KDIM + k)           = p00;
        *(u32x4*)(Wb16 + (size_t)n0 * KDIM + k + 8)       = p01;
        *(u32x4*)(Wb16 + (size_t)(n0 + 1) * KDIM + k)     = p10;
        *(u32x4*)(Wb16 + (size_t)(n0 + 1) * KDIM + k + 8) = p11;
        if (k == 0) {
            size_t bi = (size_t)g * 1024 + o;
            biasp[n0]     = Ub_r[bi] + Wb_r[bi];
            biasp[n0 + 1] = Ub_i[bi] + Wb_i[bi];
        }
    }
}

// ------------------------- GEMM + fused epilogue ----------------------------
// block: 512 threads (8 waves, 2Mx4N), C-tile 256x256, BK=64, 16x16x32 MFMA.
// LDS: 2 buffers x (A 32KB + B 32KB) = 128 KiB (dynamic; attribute set on host).
// Per-wave output 128x64 -> acc[8][4] f32x4 (128 regs, AGPR-eligible).
__global__ __launch_bounds__(512) void clstm_gemm(
    const unsigned short* __restrict__ Xb,    // 4096 x 4096 bf16
    const unsigned short* __restrict__ Wb,    // 8192 x 4096 bf16
    const float* __restrict__ biasp,          // 8192
    const float* __restrict__ c_x,            // 4096 x 2048 fp32
    float* __restrict__ out) {
    extern __shared__ char smem[];            // 131072 bytes

    const int tid  = threadIdx.x;
    const int lane = tid & 63;
    const int wave = tid >> 6;                // 0..7
    const int wm = wave >> 2, wn = wave & 3;  // 2 x 4 wave grid
    const int quad = lane >> 4, col16 = lane & 15;

    // XCD-contiguous block swizzle: nwg=512 (8|512 -> bijective), then 4x8
    // supertiles so 32 consecutive swz share 4 A-panels + 8 B-panels.
    const int bid = blockIdx.x;
    const int swz = (bid & 7) * 64 + (bid >> 3);
    const int st = swz >> 5, wi = swz & 31;
    const int mtile = (st & 3) * 4 + (wi & 3);      // 0..15
    const int ntile = (st >> 2) * 8 + (wi >> 2);    // 0..31

    // staging: per K-tile 8 global_load_lds x 16B per thread (4 A + 4 B).
    // chunk id for load i = i*512 + tid -> LDS row id>>3, slot id&7 (linear
    // dest); global source pre-swizzled: chunk fetched = slot ^ (row&7).
    const int srow  = tid >> 3;               // 0..63
    const int sslot = tid & 7;
    const unsigned short* pa[4];
    const unsigned short* pb[4];
#pragma unroll
    for (int i = 0; i < 4; ++i) {
        const int rowA = i * 64 + srow;       // 0..255
        const int c = sslot ^ (rowA & 7);
        pa[i] = Xb + (size_t)(mtile * 256 + rowA) * KDIM + c * 8;
        pb[i] = Wb + (size_t)(ntile * 256 + rowA) * KDIM + c * 8;
    }

    f32x4 acc[8][4] = {};

    // prologue: stage tile 0 into buf0 (drained at kt=0 boundary, one-time)
#pragma unroll
    for (int i = 0; i < 4; ++i) {
        async16(pa[i], smem + i * 8192 + wave * 1024);
        async16(pb[i], smem + 32768 + i * 8192 + wave * 1024);
        pa[i] += 64; pb[i] += 64;
    }

    const int rA0 = wm * 128 + col16;         // + p*32 + f*16
    const int rB0 = wn * 64 + col16;          // + n*16

#pragma unroll 2
    for (int kt = 0; kt < 64; ++kt) {
        char* sA  = smem + (kt & 1) * 65536;
        char* sB  = sA + 32768;
        char* sAn = smem + (((kt & 1) ^ 1)) * 65536;
        char* sBn = sAn + 32768;

        // Boundary: tile kt's 8 stage-loads were last issued at kt-1 phase 2
        // (~1200cyc ago > ~900cyc HBM latency) -> drain is ~free. Barrier
        // also certifies every wave's buf^1 ds_reads (tile kt-1's) retired
        // (they retire before kt-1's phase-3 MFMAs) before any wave issues
        // kt+1 stages into buf^1 below.
        asm volatile("s_waitcnt vmcnt(0)" ::: "memory");
        __builtin_amdgcn_s_barrier();

        // Hoisted reads: ONLY bfr[0..1] + af0 (8 reads) gate phase-0's first
        // MFMAs; bfr[2..3] is read inside phase 0 and retires under them.
        bf16x8 bfr[4][2];
#pragma unroll
        for (int n = 0; n < 2; ++n)
#pragma unroll
            for (int ks = 0; ks < 2; ++ks) {
                const int r = rB0 + n * 16;
                const int ch = (ks * 4 + quad) ^ (r & 7);
                bfr[n][ks] = *(const bf16x8*)(sB + r * 128 + ch * 16);
            }
        bf16x8 af[2][2][2];                   // [pingpong][f][ks], static idx
#pragma unroll
        for (int f = 0; f < 2; ++f)
#pragma unroll
            for (int ks = 0; ks < 2; ++ks) {
                const int r = rA0 + f * 16;
                const int ch = (ks * 4 + quad) ^ (r & 7);
                af[0][f][ks] = *(const bf16x8*)(sA + r * 128 + ch * 16);
            }

        // 4 phases, register-pipelined by one: phase p issues A-reads for
        // p+1 (ping-pong af), then MFMAs on af[cur] (read last phase ->
        // counted lgkm, no drain). Stage issues for kt+1 at phases 0/1/2
        // (4/2/2) so the last is ~1200cyc before the next boundary drain.
#pragma unroll
        for (int p = 0; p < 4; ++p) {
            const int cur = p & 1, nxt = cur ^ 1;
            if (p == 0) {                     // deferred B columns 2,3
#pragma unroll
                for (int n = 2; n < 4; ++n)
#pragma unroll
                    for (int ks = 0; ks < 2; ++ks) {
                        const int r = rB0 + n * 16;
                        const int ch = (ks * 4 + quad) ^ (r & 7);
                        bfr[n][ks] = *(const bf16x8*)(sB + r * 128 + ch * 16);
                    }
            }
            if (p < 3) {                      // A-frags for phase p+1
#pragma unroll
                for (int f = 0; f < 2; ++f)
#pragma unroll
                    for (int ks = 0; ks < 2; ++ks) {
                        const int r = rA0 + (p + 1) * 32 + f * 16;
                        const int ch = (ks * 4 + quad) ^ (r & 7);
                        af[nxt][f][ks] = *(const bf16x8*)(sA + r * 128 + ch * 16);
                    }
            }
            if (kt < 63) {                    // stage kt+1: 4/2/2 at p=0/1/2
                if (p == 0) {
                    async16(pa[0], sAn + 0 * 8192 + wave * 1024); pa[0] += 64;
                    async16(pb[0], sBn + 0 * 8192 + wave * 1024); pb[0] += 64;
                    async16(pa[1], sAn + 1 * 8192 + wave * 1024); pa[1] += 64;
                    async16(pb[1], sBn + 1 * 8192 + wave * 1024); pb[1] += 64;
                } else if (p == 1) {
                    async16(pa[2], sAn + 2 * 8192 + wave * 1024); pa[2] += 64;
                    async16(pb[2], sBn + 2 * 8192 + wave * 1024); pb[2] += 64;
                } else if (p == 2) {
                    async16(pa[3], sAn + 3 * 8192 + wave * 1024); pa[3] += 64;
                    async16(pb[3], sBn + 3 * 8192 + wave * 1024); pb[3] += 64;
                }
            }
            __builtin_amdgcn_s_setprio(1);
            if (p == 0) {                     // consume n={0,1} first: gated
#pragma unroll                                // on the 8 hoisted reads only
                for (int f = 0; f < 2; ++f)
#pragma unroll
                    for (int n = 0; n < 2; ++n) {
                        acc[f][n] = __builtin_amdgcn_mfma_f32_16x16x32_bf16(
                            af[0][f][0], bfr[n][0], acc[f][n], 0, 0, 0);
                        acc[f][n] = __builtin_amdgcn_mfma_f32_16x16x32_bf16(
                            af[0][f][1], bfr[n][1], acc[f][n], 0, 0, 0);
                    }
#pragma unroll
                for (int f = 0; f < 2; ++f)
#pragma unroll
                    for (int n = 2; n < 4; ++n) {
                        acc[f][n] = __builtin_amdgcn_mfma_f32_16x16x32_bf16(
                            af[0][f][0], bfr[n][0], acc[f][n], 0, 0, 0);
                        acc[f][n] = __builtin_amdgcn_mfma_f32_16x16x32_bf16(
                            af[0][f][1], bfr[n][1], acc[f][n], 0, 0, 0);
                    }
            } else {
#pragma unroll
                for (int f = 0; f < 2; ++f)
#pragma unroll
                    for (int n = 0; n < 4; ++n) {
                        acc[p * 2 + f][n] = __builtin_amdgcn_mfma_f32_16x16x32_bf16(
                            af[cur][f][0], bfr[n][0], acc[p * 2 + f][n], 0, 0, 0);
                        acc[p * 2 + f][n] = __builtin_amdgcn_mfma_f32_16x16x32_bf16(
                            af[cur][f][1], bfr[n][1], acc[p * 2 + f][n], 0, 0, 0);
                    }
            }
            __builtin_amdgcn_s_setprio(0);
        }
    }

    // ---- epilogue: per-wave LDS round trip, C-layout -> (row, o) layout ----
    // Wave tile = 128 rows x 64 cols. 8 passes of (32 rows x 32 cols):
    // pass = seg (0..3, row segment) x h (0..1, col half). zs is WAVE-PRIVATE
    // (disjoint 8KB regions): one barrier total, then intra-wave ordering only.
    // FULLY UNROLLED (rule #20): every acc index must be compile-time or the
    // whole acc array is demoted to scratch (134MB/dispatch round trip).
    __syncthreads();                          // all K-loop LDS traffic done
    float* zs = (float*)(smem + wave * 8192); // 32 rows x 40 f32 = 5120B used
    const float* bp = biasp + ntile * 256 + wn * 64;
    const int o_idx = lane & 3;
    const int rgrp  = lane >> 2;              // 0..15

#pragma unroll
    for (int pass = 0; pass < 8; ++pass) {
        const int seg = pass >> 1;            // row segment: acc mf = seg*2 + {0,1}
        const int h   = pass & 1;             // col half:   acc nf = h*2 + {0,1}
#pragma unroll
        for (int mf2 = 0; mf2 < 2; ++mf2)
#pragma unroll
            for (int tl = 0; tl < 2; ++tl) {
                int nf = h * 2 + tl;
                int colz = tl * 16 + col16;
#pragma unroll
                for (int r = 0; r < 4; ++r)
                    zs[(mf2 * 16 + quad * 4 + r) * 40 + colz] = acc[seg * 2 + mf2][nf][r];
            }
        // intra-wave RAW through LDS: compiler inserts lgkmcnt wait

        float4 bb0 = *(const float4*)(bp + h * 32 + o_idx * 8);
        float4 bb1 = *(const float4*)(bp + h * 32 + o_idx * 8 + 4);
        int o_glob = ntile * 32 + wn * 8 + h * 4 + o_idx;

#pragma unroll
        for (int t = 0; t < 2; ++t) {
            int rowz = rgrp + t * 16;         // 0..31 within segment
            const float* zp = zs + rowz * 40 + o_idx * 8;
            float4 z0 = *(const float4*)zp;
            float4 z1 = *(const float4*)(zp + 4);
            int b = mtile * 256 + wm * 128 + seg * 32 + rowz;

            float fr = sigm(z0.x + bb0.x), fi = sigm(z0.y + bb0.y);
            float ir = sigm(z0.z + bb0.z), ii = sigm(z0.w + bb0.w);
            float ar = tanh_(z1.x + bb1.x), ai = tanh_(z1.y + bb1.y);
            float og_r = sigm(z1.z + bb1.z), og_i = sigm(z1.w + bb1.w);

            float cr = c_x[(size_t)b * 2048 + o_glob];
            float ci = c_x[(size_t)b * 2048 + 1024 + o_glob];

            float ct_r = (cr * fr - ci * fi) + (ar * ir - ai * ii);
            float ct_i = (cr * fi + ci * fr) + (ar * ii + ai * ir);
            float tr = tanh_(ct_r), ti = tanh_(ct_i);
            float ht_r = og_r * tr - og_i * ti;
            float ht_i = og_r * ti + og_i * tr;

            out[(size_t)b * 2048 + o_glob]               = ht_r;
            out[(size_t)b * 2048 + 1024 + o_glob]        = ht_i;
            out[HOFF + (size_t)b * 2048 + o_glob]        = ct_r;
            out[HOFF + (size_t)b * 2048 + 1024 + o_glob] = ct_i;
        }
        if (pass < 7)                          // drain zs reads before next pass
            asm volatile("s_waitcnt lgkmcnt(0)" ::: "memory");  // overwrites zs
    }
}

// ---------------------------------------------------------------------------
extern "C" void kernel_launch(void* const* d_in, const int* in_sizes, int n_in,
                              void* d_out, int out_size, void* d_ws, size_t ws_size,
                              hipStream_t stream) {
    const float* input = (const float*)d_in[0];
    const float* h_x   = (const float*)d_in[1];
    const float* c_x   = (const float*)d_in[2];
    const float* Uw_r  = (const float*)d_in[3];
    const float* Uw_i  = (const float*)d_in[4];
    const float* Ub_r  = (const float*)d_in[5];
    const float* Ub_i  = (const float*)d_in[6];
    const float* Ww_r  = (const float*)d_in[7];
    const float* Ww_i  = (const float*)d_in[8];
    const float* Wb_r  = (const float*)d_in[9];
    const float* Wb_i  = (const float*)d_in[10];
    float* out = (float*)d_out;

    // ws layout: X bf16 (32MB) | Wbig bf16 (64MB) | bias fp32 (32KB)  ~= 96MB
    unsigned short* Xb   = (unsigned short*)d_ws;
    unsigned short* Wb16 = Xb + (size_t)4096 * 4096;
    float* biasp = (float*)(Wb16 + (size_t)8192 * 4096);

    static bool s_attr = false;               // host-side, not a stream op:
    if (!s_attr) {                            // graph-capture safe
        hipFuncSetAttribute((const void*)clstm_gemm,
                            hipFuncAttributeMaxDynamicSharedMemorySize, 131072);
        s_attr = true;
    }

    pack_all<<<8192, 256, 0, stream>>>(input, h_x, Uw_r, Uw_i, Ww_r, Ww_i,
                                       Ub_r, Ub_i, Wb_r, Wb_i, Xb, Wb16, biasp);
    clstm_gemm<<<512, 512, 131072, stream>>>(Xb, Wb16, biasp, c_x, out);
}